// Round 5
// baseline (475.292 us; speedup 1.0000x reference)
//
#include <hip/hip_runtime.h>
#include <stdint.h>

typedef unsigned short u16;
using bf16x8 = __attribute__((ext_vector_type(8))) short;
using f32x4  = __attribute__((ext_vector_type(4))) float;

__device__ __forceinline__ float bf2f(u16 u) {
  union { unsigned int i; float f; } a; a.i = ((unsigned int)u) << 16; return a.f;
}
__device__ __forceinline__ u16 f2bf(float f) {
  union { float f; unsigned int i; } a; a.f = f;
  unsigned int u = a.i;
  u += 0x7fffu + ((u >> 16) & 1u);
  return (u16)(u >> 16);
}
__device__ __forceinline__ float lrelu(float x) { return x >= 0.f ? x : 0.2f * x; }

// ---------------------------------------------------------------------------
// Kernel 1 (merged): blocks 0..1023 convert lin_w f32 -> bf16,
// block 1024 does the batch-invariant prep (kNN + relation MLP) with all
// small tables in LDS, and zeroes the BN stats accumulator.
// ---------------------------------------------------------------------------
__global__ __launch_bounds__(256) void prep_convw_kernel(
    const float* __restrict__ vert, const float* __restrict__ rw1,
    const float* __restrict__ rb1, const float* __restrict__ rw2,
    const float* __restrict__ rb2, const float* __restrict__ lw,
    u16* __restrict__ wb, float* __restrict__ e_out,
    int* __restrict__ idx_out, float* __restrict__ stats) {
  const int t = threadIdx.x;
  if (blockIdx.x < 1024) {
    // ---- lin_w f32 -> bf16, 262144 float4 groups total ----
    const int i = blockIdx.x * 256 + t;
    float4 v = ((const float4*)lw)[i];
    uint2 o;
    o.x = (unsigned)f2bf(v.x) | ((unsigned)f2bf(v.y) << 16);
    o.y = (unsigned)f2bf(v.z) | ((unsigned)f2bf(v.w) << 16);
    ((uint2*)wb)[i] = o;
    return;
  }
  // ---- prep block ----
  __shared__ float Vs[96];     // 32 vertices x 3
  __shared__ float w1s[100];
  __shared__ float b1s[10];
  __shared__ float w2s[10];
  __shared__ float b2s;
  if (t < 96)  Vs[t]  = vert[t];
  if (t < 100) w1s[t] = rw1[t];
  if (t < 10)  { b1s[t] = rb1[t]; w2s[t] = rw2[t]; }
  if (t == 0)  b2s = rb2[0];
  // zero BN stats accumulator (ws is poisoned 0xAA)
  for (int i = t; i < 2048; i += 256) stats[i] = 0.f;
  __syncthreads();
  if (t < 32) {
    const float vt0 = Vs[t*3], vt1 = Vs[t*3+1], vt2 = Vs[t*3+2];
    const float xxt = vt0*vt0 + vt1*vt1 + vt2*vt2;
    float pd[32];
    #pragma unroll
    for (int m = 0; m < 32; ++m) {
      float m0 = Vs[m*3], m1 = Vs[m*3+1], m2 = Vs[m*3+2];
      float dot = vt0*m0 + vt1*m1 + vt2*m2;
      float inner = -2.f * dot;
      float xxm = m0*m0 + m1*m1 + m2*m2;
      pd[m] = -xxt - inner - xxm;   // exactly the reference formula
    }
    // top-5 largest, ties -> lowest index (jax.lax.top_k semantics)
    int sel[5];
    unsigned taken = 0;
    #pragma unroll
    for (int k = 0; k < 5; ++k) {
      float best = -3.0e38f; int bi = 0;
      #pragma unroll
      for (int m = 0; m < 32; ++m)
        if (!((taken >> m) & 1u) && pd[m] > best) { best = pd[m]; bi = m; }
      taken |= (1u << bi);
      sel[k] = bi;
    }
    const int s0 = sel[0];
    const float v0x = Vs[s0*3], v0y = Vs[s0*3+1], v0z = Vs[s0*3+2];
    #pragma unroll
    for (int k = 0; k < 5; ++k) {
      const int si = sel[k];
      float vx = Vs[si*3], vy = Vs[si*3+1], vz = Vs[si*3+2];
      float dx = v0x - vx, dy = v0y - vy, dz = v0z - vz;
      float dn = sqrtf(dx*dx + dy*dy + dz*dz + 1e-12f);
      float vF[10] = {v0x, v0y, v0z, vx, vy, vz, dx, dy, dz, dn};
      float e = b2s;
      #pragma unroll
      for (int i = 0; i < 10; ++i) {
        float h = b1s[i];
        #pragma unroll
        for (int j = 0; j < 10; ++j) h += w1s[i*10+j] * vF[j];
        h = h > 0.f ? h : 0.f;
        e += w2s[i] * h;
      }
      e_out[t*5+k]   = e;
      idx_out[t*5+k] = sel[k];
    }
  }
}

// ---------------------------------------------------------------------------
// Kernel 2 (fused conv + gather): one block per batch of 32 views.
// Phase A: 3x3 valid conv per view, f32 img staged in LDS, bf16 results
// kept in LDS (F never touches HBM: saves 32 MB write + 32 MB read).
// Phase B: weighted k-NN gather straight from LDS -> Fa (bf16, global).
// LDS: 13872 (img) + 65536 (F) + 640 + 640 = 80688 B -> 2 blocks/CU.
// Numerics identical to the previous split kernels (same bf16 round points).
// ---------------------------------------------------------------------------
__global__ __launch_bounds__(256) void conv_gather_kernel(
    const float* __restrict__ x, const float* __restrict__ cw,
    const float* __restrict__ cb, const float* __restrict__ e,
    const int* __restrict__ idx, u16* __restrict__ Fa) {
  __shared__ __align__(16) float img[3*34*34];   // 13872 B
  __shared__ __align__(16) u16 Fl[32*1024];      // 65536 B
  __shared__ float e_s[160];
  __shared__ int   idx_s[160];
  const int t = threadIdx.x;
  const long b = blockIdx.x;                     // batch index (512 blocks)

  float w[27];
  #pragma unroll
  for (int q = 0; q < 27; ++q) w[q] = cw[q];
  const float bias = cb[0];
  if (t < 160) { e_s[t] = e[t]; idx_s[t] = idx[t]; }

  const int p0 = t * 4;
  const int i = p0 >> 5, j = p0 & 31;            // j <= 28: 4 outputs share row i
  for (int v = 0; v < 32; ++v) {
    const float4* src = (const float4*)(x + (b*32 + v) * 3468);  // 3468*4 % 16 == 0
    for (int q = t; q < 867; q += 256)
      ((float4*)img)[q] = src[q];
    __syncthreads();
    u16 r[4];
    #pragma unroll
    for (int u = 0; u < 4; ++u) {
      float acc = bias;
      #pragma unroll
      for (int c = 0; c < 3; ++c)
        #pragma unroll
        for (int dy = 0; dy < 3; ++dy)
          #pragma unroll
          for (int dxk = 0; dxk < 3; ++dxk)
            acc += w[c*9 + dy*3 + dxk] * img[c*1156 + (i+dy)*34 + (j+u+dxk)];
      r[u] = f2bf(acc);
    }
    uint2 o;
    o.x = (unsigned)r[0] | ((unsigned)r[1] << 16);
    o.y = (unsigned)r[2] | ((unsigned)r[3] << 16);
    ((uint2*)(Fl + v*1024))[t] = o;
    __syncthreads();   // protects img before next view's staging, and Fl before gather
  }
  // Phase B: gather. Thread t covers d = 4t..4t+3 for each of the 32 rows.
  for (int n = 0; n < 32; ++n) {
    float a0=0.f, a1=0.f, a2=0.f, a3=0.f;
    #pragma unroll
    for (int k = 0; k < 5; ++k) {
      const float ek = e_s[n*5+k];
      const int id = idx_s[n*5+k];
      uint2 d = ((const uint2*)(Fl + id*1024))[t];
      a0 += ek * __uint_as_float(d.x << 16);
      a1 += ek * __uint_as_float(d.x & 0xffff0000u);
      a2 += ek * __uint_as_float(d.y << 16);
      a3 += ek * __uint_as_float(d.y & 0xffff0000u);
    }
    uint2 o;
    o.x = (unsigned)f2bf(a0) | ((unsigned)f2bf(a1) << 16);
    o.y = (unsigned)f2bf(a2) | ((unsigned)f2bf(a3) << 16);
    ((uint2*)(Fa + (b*32 + n) * 1024))[t] = o;
  }
}

// ---------------------------------------------------------------------------
// Kernel 3: bf16 MFMA GEMM  z = Fa @ Wb^T + lin_b  (M x 1024 @ 1024 x 1024)
// m97 structure: 128x128 tile, BK=32, global_load_lds width 16,
// 4 waves 2x2, each wave 4x4 of 16x16x32 MFMA. z stored as bf16.
// BN sum/sumsq fused into the epilogue.
// ---------------------------------------------------------------------------
__global__ __launch_bounds__(256) void gemm_kernel(const u16* __restrict__ A,
    const u16* __restrict__ W, const float* __restrict__ linb, u16* __restrict__ z,
    float* __restrict__ stats) {
  __shared__ __align__(16) u16 At[128*32];
  __shared__ __align__(16) u16 Bt[128*32];
  const int t = threadIdx.x;
  const int lane = t & 63;
  const int w = t >> 6;
  const int lr = lane & 15, lq = lane >> 4;
  const int wm = w >> 1, wn = w & 1;
  const long m0 = (long)blockIdx.y * 128;
  const int n0 = blockIdx.x * 128;
  f32x4 acc[4][4];
  #pragma unroll
  for (int mi = 0; mi < 4; ++mi)
    #pragma unroll
    for (int ni = 0; ni < 4; ++ni) acc[mi][ni] = (f32x4){0.f, 0.f, 0.f, 0.f};
  const int srow = t >> 2;          // 0..63
  const int scol = (t & 3) * 8;     // k offset within BK tile
  for (int k0 = 0; k0 < 1024; k0 += 32) {
    #pragma unroll
    for (int h = 0; h < 2; ++h) {
      const u16* ga = A + (m0 + h*64 + srow) * 1024 + k0 + scol;
      const u16* gb = W + (long)(n0 + h*64 + srow) * 1024 + k0 + scol;
      __builtin_amdgcn_global_load_lds(
          (const __attribute__((address_space(1))) void*)ga,
          (__attribute__((address_space(3))) void*)((char*)At + h*4096 + t*16), 16, 0, 0);
      __builtin_amdgcn_global_load_lds(
          (const __attribute__((address_space(1))) void*)gb,
          (__attribute__((address_space(3))) void*)((char*)Bt + h*4096 + t*16), 16, 0, 0);
    }
    __syncthreads();
    bf16x8 af[4], bfr[4];
    #pragma unroll
    for (int i = 0; i < 4; ++i)
      af[i] = *(const bf16x8*)&At[(wm*64 + i*16 + lr)*32 + lq*8];
    #pragma unroll
    for (int i = 0; i < 4; ++i)
      bfr[i] = *(const bf16x8*)&Bt[(wn*64 + i*16 + lr)*32 + lq*8];
    #pragma unroll
    for (int mi = 0; mi < 4; ++mi)
      #pragma unroll
      for (int ni = 0; ni < 4; ++ni)
        acc[mi][ni] = __builtin_amdgcn_mfma_f32_16x16x32_bf16(af[mi], bfr[ni], acc[mi][ni], 0, 0, 0);
    __syncthreads();
  }
  // epilogue: C/D layout col=lane&15, row=(lane>>4)*4+reg (m89)
  #pragma unroll
  for (int ni = 0; ni < 4; ++ni) {
    const int col = n0 + wn*64 + ni*16 + lr;
    const float bias = linb[col];
    float s = 0.f, q = 0.f;
    #pragma unroll
    for (int mi = 0; mi < 4; ++mi) {
      const long row = m0 + wm*64 + mi*16 + lq*4;
      #pragma unroll
      for (int r = 0; r < 4; ++r) {
        const float v = acc[mi][ni][r] + bias;
        z[(row + r) * 1024 + col] = f2bf(v);
        s += v; q += v * v;
      }
    }
    // reduce over the 4 lq groups (lanes lr, lr+16, lr+32, lr+48 share col)
    s += __shfl_xor(s, 16); q += __shfl_xor(q, 16);
    s += __shfl_xor(s, 32); q += __shfl_xor(q, 32);
    if (lq == 0) {
      atomicAdd(&stats[col], s);
      atomicAdd(&stats[1024 + col], q);
    }
  }
}

// ---------------------------------------------------------------------------
// Kernel 4: normalize + LeakyReLU + f32 store, with BN finalize folded in.
// Block covers 2048 consecutive elements (2 rows of 1024).
// FIX vs round 4: column of group i is (i*8) & 1023 = (t & 127) * 8, NOT t*8
// (t >= 128 overflowed into sumsq / past the stats buffer -> NaN).
// ---------------------------------------------------------------------------
__global__ __launch_bounds__(256) void norm_kernel(const u16* __restrict__ z,
    const float* __restrict__ stats, const float* __restrict__ g,
    const float* __restrict__ bb, float invM, float* __restrict__ out) {
  const int t = threadIdx.x;
  const long i = (long)blockIdx.x * 256 + t;   // 8-elem group index
  uint4 d = ((const uint4*)z)[i];
  const int c = (t & 127) * 8;                 // (i*8) & 1023
  float vv[8];
  vv[0] = __uint_as_float(d.x << 16); vv[1] = __uint_as_float(d.x & 0xffff0000u);
  vv[2] = __uint_as_float(d.y << 16); vv[3] = __uint_as_float(d.y & 0xffff0000u);
  vv[4] = __uint_as_float(d.z << 16); vv[5] = __uint_as_float(d.z & 0xffff0000u);
  vv[6] = __uint_as_float(d.w << 16); vv[7] = __uint_as_float(d.w & 0xffff0000u);
  float y[8];
  #pragma unroll
  for (int j = 0; j < 8; ++j) {
    const int cj = c + j;
    const float mean = stats[cj] * invM;
    const float var  = stats[1024+cj] * invM - mean*mean;
    const float sc = g[cj] * rsqrtf(var + 1e-5f);
    const float sh = bb[cj] - mean * sc;
    y[j] = lrelu(vv[j] * sc + sh);
  }
  float4 o0 = {y[0], y[1], y[2], y[3]};
  float4 o1 = {y[4], y[5], y[6], y[7]};
  ((float4*)out)[i*2]   = o0;
  ((float4*)out)[i*2+1] = o1;
}

extern "C" void kernel_launch(void* const* d_in, const int* in_sizes, int n_in,
                              void* d_out, int out_size, void* d_ws, size_t ws_size,
                              hipStream_t stream) {
  const float* x    = (const float*)d_in[0];
  const float* vert = (const float*)d_in[1];
  const float* cw   = (const float*)d_in[2];
  const float* cb   = (const float*)d_in[3];
  const float* rw1  = (const float*)d_in[4];
  const float* rb1  = (const float*)d_in[5];
  const float* rw2  = (const float*)d_in[6];
  const float* rb2  = (const float*)d_in[7];
  const float* lw   = (const float*)d_in[8];
  const float* lb   = (const float*)d_in[9];
  const float* bng  = (const float*)d_in[10];
  const float* bnb  = (const float*)d_in[11];
  float* out = (float*)d_out;

  const int n_img = in_sizes[0] / (3*34*34);   // B*32 = 16384
  const size_t faBytes = (size_t)n_img * 1024 * 2;   // 32 MB

  char* ws = (char*)d_ws;
  u16*  Fa = (u16*)ws;                    // [0, 32MB)
  u16*  z  = (u16*)(ws + faBytes);        // [32, 64MB)
  char* sp = ws + 2*faBytes;              // smalls at 64MB
  float* e_buf   = (float*)sp;            // 640 B
  int*   idx_buf = (int*)(sp + 1024);     // 640 B
  float* stats   = (float*)(sp + 2048);   // 8 KB (sum | sumsq)
  u16*   Wb      = (u16*)(sp + 16384);    // 2 MB bf16 lin_w

  prep_convw_kernel<<<1025, 256, 0, stream>>>(vert, rw1, rb1, rw2, rb2, lw, Wb,
                                              e_buf, idx_buf, stats);
  conv_gather_kernel<<<n_img/32, 256, 0, stream>>>(x, cw, cb, e_buf, idx_buf, Fa);
  gemm_kernel<<<dim3(8, n_img/128), 256, 0, stream>>>(Fa, Wb, lb, z, stats);
  norm_kernel<<<n_img/2, 256, 0, stream>>>(z, stats, bng, bnb, 1.f/(float)n_img, out);
}

// Round 6
// 461.851 us; speedup vs baseline: 1.0291x; 1.0291x over previous
//
#include <hip/hip_runtime.h>
#include <stdint.h>

typedef unsigned short u16;
using bf16x8 = __attribute__((ext_vector_type(8))) short;
using f32x4  = __attribute__((ext_vector_type(4))) float;

__device__ __forceinline__ float bf2f(u16 u) {
  union { unsigned int i; float f; } a; a.i = ((unsigned int)u) << 16; return a.f;
}
__device__ __forceinline__ u16 f2bf(float f) {
  union { float f; unsigned int i; } a; a.f = f;
  unsigned int u = a.i;
  u += 0x7fffu + ((u >> 16) & 1u);
  return (u16)(u >> 16);
}
__device__ __forceinline__ float lrelu(float x) { return x >= 0.f ? x : 0.2f * x; }

// ---------------------------------------------------------------------------
// Kernel 1 (merged): blocks 0..1023 convert lin_w f32 -> bf16,
// block 1024 does the batch-invariant prep (kNN + relation MLP) with all
// small tables in LDS, and zeroes the BN stats accumulator.
// ---------------------------------------------------------------------------
__global__ __launch_bounds__(256) void prep_convw_kernel(
    const float* __restrict__ vert, const float* __restrict__ rw1,
    const float* __restrict__ rb1, const float* __restrict__ rw2,
    const float* __restrict__ rb2, const float* __restrict__ lw,
    u16* __restrict__ wb, float* __restrict__ e_out,
    int* __restrict__ idx_out, float* __restrict__ stats) {
  const int t = threadIdx.x;
  if (blockIdx.x < 1024) {
    // ---- lin_w f32 -> bf16, 262144 float4 groups total ----
    const int i = blockIdx.x * 256 + t;
    float4 v = ((const float4*)lw)[i];
    uint2 o;
    o.x = (unsigned)f2bf(v.x) | ((unsigned)f2bf(v.y) << 16);
    o.y = (unsigned)f2bf(v.z) | ((unsigned)f2bf(v.w) << 16);
    ((uint2*)wb)[i] = o;
    return;
  }
  // ---- prep block ----
  __shared__ float Vs[96];     // 32 vertices x 3
  __shared__ float w1s[100];
  __shared__ float b1s[10];
  __shared__ float w2s[10];
  __shared__ float b2s;
  if (t < 96)  Vs[t]  = vert[t];
  if (t < 100) w1s[t] = rw1[t];
  if (t < 10)  { b1s[t] = rb1[t]; w2s[t] = rw2[t]; }
  if (t == 0)  b2s = rb2[0];
  // zero BN stats accumulator (ws is poisoned 0xAA)
  for (int i = t; i < 2048; i += 256) stats[i] = 0.f;
  __syncthreads();
  if (t < 32) {
    const float vt0 = Vs[t*3], vt1 = Vs[t*3+1], vt2 = Vs[t*3+2];
    const float xxt = vt0*vt0 + vt1*vt1 + vt2*vt2;
    float pd[32];
    #pragma unroll
    for (int m = 0; m < 32; ++m) {
      float m0 = Vs[m*3], m1 = Vs[m*3+1], m2 = Vs[m*3+2];
      float dot = vt0*m0 + vt1*m1 + vt2*m2;
      float inner = -2.f * dot;
      float xxm = m0*m0 + m1*m1 + m2*m2;
      pd[m] = -xxt - inner - xxm;   // exactly the reference formula
    }
    // top-5 largest, ties -> lowest index (jax.lax.top_k semantics)
    int sel[5];
    unsigned taken = 0;
    #pragma unroll
    for (int k = 0; k < 5; ++k) {
      float best = -3.0e38f; int bi = 0;
      #pragma unroll
      for (int m = 0; m < 32; ++m)
        if (!((taken >> m) & 1u) && pd[m] > best) { best = pd[m]; bi = m; }
      taken |= (1u << bi);
      sel[k] = bi;
    }
    const int s0 = sel[0];
    const float v0x = Vs[s0*3], v0y = Vs[s0*3+1], v0z = Vs[s0*3+2];
    #pragma unroll
    for (int k = 0; k < 5; ++k) {
      const int si = sel[k];
      float vx = Vs[si*3], vy = Vs[si*3+1], vz = Vs[si*3+2];
      float dx = v0x - vx, dy = v0y - vy, dz = v0z - vz;
      float dn = sqrtf(dx*dx + dy*dy + dz*dz + 1e-12f);
      float vF[10] = {v0x, v0y, v0z, vx, vy, vz, dx, dy, dz, dn};
      float e = b2s;
      #pragma unroll
      for (int i = 0; i < 10; ++i) {
        float h = b1s[i];
        #pragma unroll
        for (int j = 0; j < 10; ++j) h += w1s[i*10+j] * vF[j];
        h = h > 0.f ? h : 0.f;
        e += w2s[i] * h;
      }
      e_out[t*5+k]   = e;
      idx_out[t*5+k] = sel[k];
    }
  }
}

// ---------------------------------------------------------------------------
// Kernel 2: 3x3 valid conv (3ch -> 1ch), f32 in -> bf16 F out.
// One block per image (16384 blocks — full latency hiding; the round-5
// fused variant at 512 blocks was latency-bound at 13% BW, reverted).
// ---------------------------------------------------------------------------
__global__ __launch_bounds__(256) void conv_kernel(const float* __restrict__ x,
    const float* __restrict__ cw, const float* __restrict__ cb, u16* __restrict__ F) {
  __shared__ __align__(16) float lds[3*34*34];  // 3468 floats
  const int t = threadIdx.x;
  const long img = blockIdx.x;
  const float4* src = (const float4*)(x + img * 3468);   // 3468*4 % 16 == 0
  for (int q = t; q < 867; q += 256)
    ((float4*)lds)[q] = src[q];
  float w[27];
  #pragma unroll
  for (int q = 0; q < 27; ++q) w[q] = cw[q];
  const float bias = cb[0];
  __syncthreads();
  const int p0 = t * 4;
  const int i = p0 >> 5, j = p0 & 31;   // j <= 28, so 4 outputs share row i
  u16 r[4];
  #pragma unroll
  for (int u = 0; u < 4; ++u) {
    float acc = bias;
    #pragma unroll
    for (int c = 0; c < 3; ++c)
      #pragma unroll
      for (int dy = 0; dy < 3; ++dy)
        #pragma unroll
        for (int dxk = 0; dxk < 3; ++dxk)
          acc += w[c*9 + dy*3 + dxk] * lds[c*1156 + (i+dy)*34 + (j+u+dxk)];
    r[u] = f2bf(acc);
  }
  uint2 o;
  o.x = (unsigned)r[0] | ((unsigned)r[1] << 16);
  o.y = (unsigned)r[2] | ((unsigned)r[3] << 16);
  ((uint2*)(F + img*1024))[t] = o;
}

// ---------------------------------------------------------------------------
// Kernel 3: weighted k-NN gather: Fa[b,n,:] = sum_k e[n,k] * F[b,idx[n,k],:]
// ---------------------------------------------------------------------------
__global__ __launch_bounds__(256) void gather_kernel(const u16* __restrict__ F,
    const float* __restrict__ e, const int* __restrict__ idx, u16* __restrict__ Fa) {
  const int g = blockIdx.x;
  const int b = g >> 5, n = g & 31;
  const int t = threadIdx.x;
  float a0=0.f, a1=0.f, a2=0.f, a3=0.f;
  #pragma unroll
  for (int k = 0; k < 5; ++k) {
    const float ek = e[n*5+k];
    const int id = idx[n*5+k];
    uint2 d = ((const uint2*)(F + ((long)(b*32 + id)) * 1024))[t];
    a0 += ek * __uint_as_float(d.x << 16);
    a1 += ek * __uint_as_float(d.x & 0xffff0000u);
    a2 += ek * __uint_as_float(d.y << 16);
    a3 += ek * __uint_as_float(d.y & 0xffff0000u);
  }
  uint2 o;
  o.x = (unsigned)f2bf(a0) | ((unsigned)f2bf(a1) << 16);
  o.y = (unsigned)f2bf(a2) | ((unsigned)f2bf(a3) << 16);
  ((uint2*)(Fa + (long)g * 1024))[t] = o;
}

// ---------------------------------------------------------------------------
// Kernel 4: bf16 MFMA GEMM  z = Fa @ Wb^T + lin_b  (M x 1024 @ 1024 x 1024)
// m97 structure: 128x128 tile, BK=32, global_load_lds width 16,
// 4 waves 2x2, each wave 4x4 of 16x16x32 MFMA. z stored as bf16.
// BN sum/sumsq fused into the epilogue.
// ---------------------------------------------------------------------------
__global__ __launch_bounds__(256) void gemm_kernel(const u16* __restrict__ A,
    const u16* __restrict__ W, const float* __restrict__ linb, u16* __restrict__ z,
    float* __restrict__ stats) {
  __shared__ __align__(16) u16 At[128*32];
  __shared__ __align__(16) u16 Bt[128*32];
  const int t = threadIdx.x;
  const int lane = t & 63;
  const int w = t >> 6;
  const int lr = lane & 15, lq = lane >> 4;
  const int wm = w >> 1, wn = w & 1;
  const long m0 = (long)blockIdx.y * 128;
  const int n0 = blockIdx.x * 128;
  f32x4 acc[4][4];
  #pragma unroll
  for (int mi = 0; mi < 4; ++mi)
    #pragma unroll
    for (int ni = 0; ni < 4; ++ni) acc[mi][ni] = (f32x4){0.f, 0.f, 0.f, 0.f};
  const int srow = t >> 2;          // 0..63
  const int scol = (t & 3) * 8;     // k offset within BK tile
  for (int k0 = 0; k0 < 1024; k0 += 32) {
    #pragma unroll
    for (int h = 0; h < 2; ++h) {
      const u16* ga = A + (m0 + h*64 + srow) * 1024 + k0 + scol;
      const u16* gb = W + (long)(n0 + h*64 + srow) * 1024 + k0 + scol;
      __builtin_amdgcn_global_load_lds(
          (const __attribute__((address_space(1))) void*)ga,
          (__attribute__((address_space(3))) void*)((char*)At + h*4096 + t*16), 16, 0, 0);
      __builtin_amdgcn_global_load_lds(
          (const __attribute__((address_space(1))) void*)gb,
          (__attribute__((address_space(3))) void*)((char*)Bt + h*4096 + t*16), 16, 0, 0);
    }
    __syncthreads();
    bf16x8 af[4], bfr[4];
    #pragma unroll
    for (int i = 0; i < 4; ++i)
      af[i] = *(const bf16x8*)&At[(wm*64 + i*16 + lr)*32 + lq*8];
    #pragma unroll
    for (int i = 0; i < 4; ++i)
      bfr[i] = *(const bf16x8*)&Bt[(wn*64 + i*16 + lr)*32 + lq*8];
    #pragma unroll
    for (int mi = 0; mi < 4; ++mi)
      #pragma unroll
      for (int ni = 0; ni < 4; ++ni)
        acc[mi][ni] = __builtin_amdgcn_mfma_f32_16x16x32_bf16(af[mi], bfr[ni], acc[mi][ni], 0, 0, 0);
    __syncthreads();
  }
  // epilogue: C/D layout col=lane&15, row=(lane>>4)*4+reg (m89)
  #pragma unroll
  for (int ni = 0; ni < 4; ++ni) {
    const int col = n0 + wn*64 + ni*16 + lr;
    const float bias = linb[col];
    float s = 0.f, q = 0.f;
    #pragma unroll
    for (int mi = 0; mi < 4; ++mi) {
      const long row = m0 + wm*64 + mi*16 + lq*4;
      #pragma unroll
      for (int r = 0; r < 4; ++r) {
        const float v = acc[mi][ni][r] + bias;
        z[(row + r) * 1024 + col] = f2bf(v);
        s += v; q += v * v;
      }
    }
    // reduce over the 4 lq groups (lanes lr, lr+16, lr+32, lr+48 share col)
    s += __shfl_xor(s, 16); q += __shfl_xor(q, 16);
    s += __shfl_xor(s, 32); q += __shfl_xor(q, 32);
    if (lq == 0) {
      atomicAdd(&stats[col], s);
      atomicAdd(&stats[1024 + col], q);
    }
  }
}

// ---------------------------------------------------------------------------
// Kernel 5: normalize + LeakyReLU + f32 store, with BN finalize folded in.
// Block covers 2048 consecutive elements (2 rows of 1024).
// Column of 8-elem group i is (i*8) & 1023 = (t & 127) * 8.
// ---------------------------------------------------------------------------
__global__ __launch_bounds__(256) void norm_kernel(const u16* __restrict__ z,
    const float* __restrict__ stats, const float* __restrict__ g,
    const float* __restrict__ bb, float invM, float* __restrict__ out) {
  const int t = threadIdx.x;
  const long i = (long)blockIdx.x * 256 + t;   // 8-elem group index
  uint4 d = ((const uint4*)z)[i];
  const int c = (t & 127) * 8;                 // (i*8) & 1023
  float vv[8];
  vv[0] = __uint_as_float(d.x << 16); vv[1] = __uint_as_float(d.x & 0xffff0000u);
  vv[2] = __uint_as_float(d.y << 16); vv[3] = __uint_as_float(d.y & 0xffff0000u);
  vv[4] = __uint_as_float(d.z << 16); vv[5] = __uint_as_float(d.z & 0xffff0000u);
  vv[6] = __uint_as_float(d.w << 16); vv[7] = __uint_as_float(d.w & 0xffff0000u);
  float y[8];
  #pragma unroll
  for (int j = 0; j < 8; ++j) {
    const int cj = c + j;
    const float mean = stats[cj] * invM;
    const float var  = stats[1024+cj] * invM - mean*mean;
    const float sc = g[cj] * rsqrtf(var + 1e-5f);
    const float sh = bb[cj] - mean * sc;
    y[j] = lrelu(vv[j] * sc + sh);
  }
  float4 o0 = {y[0], y[1], y[2], y[3]};
  float4 o1 = {y[4], y[5], y[6], y[7]};
  ((float4*)out)[i*2]   = o0;
  ((float4*)out)[i*2+1] = o1;
}

extern "C" void kernel_launch(void* const* d_in, const int* in_sizes, int n_in,
                              void* d_out, int out_size, void* d_ws, size_t ws_size,
                              hipStream_t stream) {
  const float* x    = (const float*)d_in[0];
  const float* vert = (const float*)d_in[1];
  const float* cw   = (const float*)d_in[2];
  const float* cb   = (const float*)d_in[3];
  const float* rw1  = (const float*)d_in[4];
  const float* rb1  = (const float*)d_in[5];
  const float* rw2  = (const float*)d_in[6];
  const float* rb2  = (const float*)d_in[7];
  const float* lw   = (const float*)d_in[8];
  const float* lb   = (const float*)d_in[9];
  const float* bng  = (const float*)d_in[10];
  const float* bnb  = (const float*)d_in[11];
  float* out = (float*)d_out;

  const int n_img = in_sizes[0] / (3*34*34);   // B*32 = 16384
  const size_t faBytes = (size_t)n_img * 1024 * 2;   // 32 MB

  char* ws = (char*)d_ws;
  u16*  Fa = (u16*)ws;                    // [0, 32MB)
  u16*  F  = (u16*)(ws + faBytes);        // [32, 64MB) — dead after gather
  u16*  z  = (u16*)(ws + faBytes);        // [32, 64MB) — overwrites dead F
  char* sp = ws + 2*faBytes;              // smalls at 64MB
  float* e_buf   = (float*)sp;            // 640 B
  int*   idx_buf = (int*)(sp + 1024);     // 640 B
  float* stats   = (float*)(sp + 2048);   // 8 KB (sum | sumsq)
  u16*   Wb      = (u16*)(sp + 16384);    // 2 MB bf16 lin_w

  prep_convw_kernel<<<1025, 256, 0, stream>>>(vert, rw1, rb1, rw2, rb2, lw, Wb,
                                              e_buf, idx_buf, stats);
  conv_kernel<<<n_img, 256, 0, stream>>>(x, cw, cb, F);
  gather_kernel<<<n_img, 256, 0, stream>>>(F, e_buf, idx_buf, Fa);
  gemm_kernel<<<dim3(8, n_img/128), 256, 0, stream>>>(Fa, Wb, lb, z, stats);
  norm_kernel<<<n_img/2, 256, 0, stream>>>(z, stats, bng, bnb, 1.f/(float)n_img, out);
}

// Round 7
// 459.143 us; speedup vs baseline: 1.0352x; 1.0059x over previous
//
#include <hip/hip_runtime.h>
#include <stdint.h>

typedef unsigned short u16;
using bf16x8 = __attribute__((ext_vector_type(8))) short;
using f32x4  = __attribute__((ext_vector_type(4))) float;

__device__ __forceinline__ float bf2f(u16 u) {
  union { unsigned int i; float f; } a; a.i = ((unsigned int)u) << 16; return a.f;
}
__device__ __forceinline__ u16 f2bf(float f) {
  union { float f; unsigned int i; } a; a.f = f;
  unsigned int u = a.i;
  u += 0x7fffu + ((u >> 16) & 1u);
  return (u16)(u >> 16);
}
__device__ __forceinline__ float lrelu(float x) { return x >= 0.f ? x : 0.2f * x; }

// ---------------------------------------------------------------------------
// Kernel 1 (merged): blocks 0..1023 convert lin_w f32 -> bf16,
// block 1024 does the batch-invariant prep (kNN + relation MLP) with all
// small tables in LDS, and zeroes the BN stats accumulator.
// ---------------------------------------------------------------------------
__global__ __launch_bounds__(256) void prep_convw_kernel(
    const float* __restrict__ vert, const float* __restrict__ rw1,
    const float* __restrict__ rb1, const float* __restrict__ rw2,
    const float* __restrict__ rb2, const float* __restrict__ lw,
    u16* __restrict__ wb, float* __restrict__ e_out,
    int* __restrict__ idx_out, float* __restrict__ stats) {
  const int t = threadIdx.x;
  if (blockIdx.x < 1024) {
    // ---- lin_w f32 -> bf16, 262144 float4 groups total ----
    const int i = blockIdx.x * 256 + t;
    float4 v = ((const float4*)lw)[i];
    uint2 o;
    o.x = (unsigned)f2bf(v.x) | ((unsigned)f2bf(v.y) << 16);
    o.y = (unsigned)f2bf(v.z) | ((unsigned)f2bf(v.w) << 16);
    ((uint2*)wb)[i] = o;
    return;
  }
  // ---- prep block ----
  __shared__ float Vs[96];     // 32 vertices x 3
  __shared__ float w1s[100];
  __shared__ float b1s[10];
  __shared__ float w2s[10];
  __shared__ float b2s;
  if (t < 96)  Vs[t]  = vert[t];
  if (t < 100) w1s[t] = rw1[t];
  if (t < 10)  { b1s[t] = rb1[t]; w2s[t] = rw2[t]; }
  if (t == 0)  b2s = rb2[0];
  // zero BN stats accumulator (ws is poisoned 0xAA)
  for (int i = t; i < 2048; i += 256) stats[i] = 0.f;
  __syncthreads();
  if (t < 32) {
    const float vt0 = Vs[t*3], vt1 = Vs[t*3+1], vt2 = Vs[t*3+2];
    const float xxt = vt0*vt0 + vt1*vt1 + vt2*vt2;
    float pd[32];
    #pragma unroll
    for (int m = 0; m < 32; ++m) {
      float m0 = Vs[m*3], m1 = Vs[m*3+1], m2 = Vs[m*3+2];
      float dot = vt0*m0 + vt1*m1 + vt2*m2;
      float inner = -2.f * dot;
      float xxm = m0*m0 + m1*m1 + m2*m2;
      pd[m] = -xxt - inner - xxm;   // exactly the reference formula
    }
    // top-5 largest, ties -> lowest index (jax.lax.top_k semantics)
    int sel[5];
    unsigned taken = 0;
    #pragma unroll
    for (int k = 0; k < 5; ++k) {
      float best = -3.0e38f; int bi = 0;
      #pragma unroll
      for (int m = 0; m < 32; ++m)
        if (!((taken >> m) & 1u) && pd[m] > best) { best = pd[m]; bi = m; }
      taken |= (1u << bi);
      sel[k] = bi;
    }
    const int s0 = sel[0];
    const float v0x = Vs[s0*3], v0y = Vs[s0*3+1], v0z = Vs[s0*3+2];
    #pragma unroll
    for (int k = 0; k < 5; ++k) {
      const int si = sel[k];
      float vx = Vs[si*3], vy = Vs[si*3+1], vz = Vs[si*3+2];
      float dx = v0x - vx, dy = v0y - vy, dz = v0z - vz;
      float dn = sqrtf(dx*dx + dy*dy + dz*dz + 1e-12f);
      float vF[10] = {v0x, v0y, v0z, vx, vy, vz, dx, dy, dz, dn};
      float e = b2s;
      #pragma unroll
      for (int i = 0; i < 10; ++i) {
        float h = b1s[i];
        #pragma unroll
        for (int j = 0; j < 10; ++j) h += w1s[i*10+j] * vF[j];
        h = h > 0.f ? h : 0.f;
        e += w2s[i] * h;
      }
      e_out[t*5+k]   = e;
      idx_out[t*5+k] = sel[k];
    }
  }
}

// ---------------------------------------------------------------------------
// Kernel 2: 3x3 valid conv (3ch -> 1ch), f32 in -> bf16 F out.
// One block per image. Round-6 finding: the old inner loop issued 108
// ds_read_b32 per thread (27 taps x 4 outputs) -> LDS-throughput-bound
// (~626 cy/wave vs ~140 cy HBM share). Now: per (ch,dy) load the 6 needed
// columns as 3x float2 (ds_read_b64, 8B-aligned: row stride 136B, j even)
// and compute all 4 outputs from registers: 27 LDS instrs/thread.
// FMA statement order identical to before -> bit-identical results.
// ---------------------------------------------------------------------------
__global__ __launch_bounds__(256) void conv_kernel(const float* __restrict__ x,
    const float* __restrict__ cw, const float* __restrict__ cb, u16* __restrict__ F) {
  __shared__ __align__(16) float lds[3*34*34];  // 3468 floats
  const int t = threadIdx.x;
  const long img = blockIdx.x;
  const float4* src = (const float4*)(x + img * 3468);   // 3468*4 % 16 == 0
  for (int q = t; q < 867; q += 256)
    ((float4*)lds)[q] = src[q];
  float w[27];
  #pragma unroll
  for (int q = 0; q < 27; ++q) w[q] = cw[q];
  const float bias = cb[0];
  __syncthreads();
  const int p0 = t * 4;
  const int i = p0 >> 5, j = p0 & 31;   // j in {0,4,...,28}: even -> 8B aligned
  float acc0 = bias, acc1 = bias, acc2 = bias, acc3 = bias;
  #pragma unroll
  for (int c = 0; c < 3; ++c) {
    #pragma unroll
    for (int dy = 0; dy < 3; ++dy) {
      const float* rp = &lds[c*1156 + (i+dy)*34 + j];
      const float2 pA = *(const float2*)(rp);
      const float2 pB = *(const float2*)(rp + 2);
      const float2 pC = *(const float2*)(rp + 4);
      const float v0 = pA.x, v1 = pA.y, v2 = pB.x, v3 = pB.y, v4 = pC.x, v5 = pC.y;
      const float w0 = w[c*9 + dy*3 + 0];
      const float w1 = w[c*9 + dy*3 + 1];
      const float w2 = w[c*9 + dy*3 + 2];
      acc0 += w0 * v0; acc0 += w1 * v1; acc0 += w2 * v2;
      acc1 += w0 * v1; acc1 += w1 * v2; acc1 += w2 * v3;
      acc2 += w0 * v2; acc2 += w1 * v3; acc2 += w2 * v4;
      acc3 += w0 * v3; acc3 += w1 * v4; acc3 += w2 * v5;
    }
  }
  uint2 o;
  o.x = (unsigned)f2bf(acc0) | ((unsigned)f2bf(acc1) << 16);
  o.y = (unsigned)f2bf(acc2) | ((unsigned)f2bf(acc3) << 16);
  ((uint2*)(F + img*1024))[t] = o;
}

// ---------------------------------------------------------------------------
// Kernel 3: weighted k-NN gather: Fa[b,n,:] = sum_k e[n,k] * F[b,idx[n,k],:]
// ---------------------------------------------------------------------------
__global__ __launch_bounds__(256) void gather_kernel(const u16* __restrict__ F,
    const float* __restrict__ e, const int* __restrict__ idx, u16* __restrict__ Fa) {
  const int g = blockIdx.x;
  const int b = g >> 5, n = g & 31;
  const int t = threadIdx.x;
  float a0=0.f, a1=0.f, a2=0.f, a3=0.f;
  #pragma unroll
  for (int k = 0; k < 5; ++k) {
    const float ek = e[n*5+k];
    const int id = idx[n*5+k];
    uint2 d = ((const uint2*)(F + ((long)(b*32 + id)) * 1024))[t];
    a0 += ek * __uint_as_float(d.x << 16);
    a1 += ek * __uint_as_float(d.x & 0xffff0000u);
    a2 += ek * __uint_as_float(d.y << 16);
    a3 += ek * __uint_as_float(d.y & 0xffff0000u);
  }
  uint2 o;
  o.x = (unsigned)f2bf(a0) | ((unsigned)f2bf(a1) << 16);
  o.y = (unsigned)f2bf(a2) | ((unsigned)f2bf(a3) << 16);
  ((uint2*)(Fa + (long)g * 1024))[t] = o;
}

// ---------------------------------------------------------------------------
// Kernel 4: bf16 MFMA GEMM  z = Fa @ Wb^T + lin_b  (M x 1024 @ 1024 x 1024)
// m97 structure: 128x128 tile, BK=32, global_load_lds width 16,
// 4 waves 2x2, each wave 4x4 of 16x16x32 MFMA. z stored as bf16.
// BN sum/sumsq fused into the epilogue.
// NEW: XCD-aware bijective swizzle (nwg=1024 % 8 == 0): each XCD owns 16
// consecutive m-tiles x all 8 n-tiles -> W (2MB) stays hot in its 4MB L2.
// ---------------------------------------------------------------------------
__global__ __launch_bounds__(256) void gemm_kernel(const u16* __restrict__ A,
    const u16* __restrict__ W, const float* __restrict__ linb, u16* __restrict__ z,
    float* __restrict__ stats) {
  __shared__ __align__(16) u16 At[128*32];
  __shared__ __align__(16) u16 Bt[128*32];
  const int t = threadIdx.x;
  const int lane = t & 63;
  const int w = t >> 6;
  const int lr = lane & 15, lq = lane >> 4;
  const int wm = w >> 1, wn = w & 1;
  // XCD swizzle: flat % 8 = XCD (dispatch round-robin); give XCD k m-tiles
  // [k*16, k*16+16) x all n-tiles.
  const int flat = blockIdx.y * 8 + blockIdx.x;
  const int sw = (flat & 7) * 128 + (flat >> 3);
  const int n0 = (sw & 7) * 128;
  const long m0 = (long)(sw >> 3) * 128;
  f32x4 acc[4][4];
  #pragma unroll
  for (int mi = 0; mi < 4; ++mi)
    #pragma unroll
    for (int ni = 0; ni < 4; ++ni) acc[mi][ni] = (f32x4){0.f, 0.f, 0.f, 0.f};
  const int srow = t >> 2;          // 0..63
  const int scol = (t & 3) * 8;     // k offset within BK tile
  for (int k0 = 0; k0 < 1024; k0 += 32) {
    #pragma unroll
    for (int h = 0; h < 2; ++h) {
      const u16* ga = A + (m0 + h*64 + srow) * 1024 + k0 + scol;
      const u16* gb = W + (long)(n0 + h*64 + srow) * 1024 + k0 + scol;
      __builtin_amdgcn_global_load_lds(
          (const __attribute__((address_space(1))) void*)ga,
          (__attribute__((address_space(3))) void*)((char*)At + h*4096 + t*16), 16, 0, 0);
      __builtin_amdgcn_global_load_lds(
          (const __attribute__((address_space(1))) void*)gb,
          (__attribute__((address_space(3))) void*)((char*)Bt + h*4096 + t*16), 16, 0, 0);
    }
    __syncthreads();
    bf16x8 af[4], bfr[4];
    #pragma unroll
    for (int i = 0; i < 4; ++i)
      af[i] = *(const bf16x8*)&At[(wm*64 + i*16 + lr)*32 + lq*8];
    #pragma unroll
    for (int i = 0; i < 4; ++i)
      bfr[i] = *(const bf16x8*)&Bt[(wn*64 + i*16 + lr)*32 + lq*8];
    #pragma unroll
    for (int mi = 0; mi < 4; ++mi)
      #pragma unroll
      for (int ni = 0; ni < 4; ++ni)
        acc[mi][ni] = __builtin_amdgcn_mfma_f32_16x16x32_bf16(af[mi], bfr[ni], acc[mi][ni], 0, 0, 0);
    __syncthreads();
  }
  // epilogue: C/D layout col=lane&15, row=(lane>>4)*4+reg (m89)
  #pragma unroll
  for (int ni = 0; ni < 4; ++ni) {
    const int col = n0 + wn*64 + ni*16 + lr;
    const float bias = linb[col];
    float s = 0.f, q = 0.f;
    #pragma unroll
    for (int mi = 0; mi < 4; ++mi) {
      const long row = m0 + wm*64 + mi*16 + lq*4;
      #pragma unroll
      for (int r = 0; r < 4; ++r) {
        const float v = acc[mi][ni][r] + bias;
        z[(row + r) * 1024 + col] = f2bf(v);
        s += v; q += v * v;
      }
    }
    // reduce over the 4 lq groups (lanes lr, lr+16, lr+32, lr+48 share col)
    s += __shfl_xor(s, 16); q += __shfl_xor(q, 16);
    s += __shfl_xor(s, 32); q += __shfl_xor(q, 32);
    if (lq == 0) {
      atomicAdd(&stats[col], s);
      atomicAdd(&stats[1024 + col], q);
    }
  }
}

// ---------------------------------------------------------------------------
// Kernel 5: normalize + LeakyReLU + f32 store, with BN finalize folded in.
// Block covers 2048 consecutive elements (2 rows of 1024).
// Column of 8-elem group i is (i*8) & 1023 = (t & 127) * 8.
// ---------------------------------------------------------------------------
__global__ __launch_bounds__(256) void norm_kernel(const u16* __restrict__ z,
    const float* __restrict__ stats, const float* __restrict__ g,
    const float* __restrict__ bb, float invM, float* __restrict__ out) {
  const int t = threadIdx.x;
  const long i = (long)blockIdx.x * 256 + t;   // 8-elem group index
  uint4 d = ((const uint4*)z)[i];
  const int c = (t & 127) * 8;                 // (i*8) & 1023
  float vv[8];
  vv[0] = __uint_as_float(d.x << 16); vv[1] = __uint_as_float(d.x & 0xffff0000u);
  vv[2] = __uint_as_float(d.y << 16); vv[3] = __uint_as_float(d.y & 0xffff0000u);
  vv[4] = __uint_as_float(d.z << 16); vv[5] = __uint_as_float(d.z & 0xffff0000u);
  vv[6] = __uint_as_float(d.w << 16); vv[7] = __uint_as_float(d.w & 0xffff0000u);
  float y[8];
  #pragma unroll
  for (int j = 0; j < 8; ++j) {
    const int cj = c + j;
    const float mean = stats[cj] * invM;
    const float var  = stats[1024+cj] * invM - mean*mean;
    const float sc = g[cj] * rsqrtf(var + 1e-5f);
    const float sh = bb[cj] - mean * sc;
    y[j] = lrelu(vv[j] * sc + sh);
  }
  float4 o0 = {y[0], y[1], y[2], y[3]};
  float4 o1 = {y[4], y[5], y[6], y[7]};
  ((float4*)out)[i*2]   = o0;
  ((float4*)out)[i*2+1] = o1;
}

extern "C" void kernel_launch(void* const* d_in, const int* in_sizes, int n_in,
                              void* d_out, int out_size, void* d_ws, size_t ws_size,
                              hipStream_t stream) {
  const float* x    = (const float*)d_in[0];
  const float* vert = (const float*)d_in[1];
  const float* cw   = (const float*)d_in[2];
  const float* cb   = (const float*)d_in[3];
  const float* rw1  = (const float*)d_in[4];
  const float* rb1  = (const float*)d_in[5];
  const float* rw2  = (const float*)d_in[6];
  const float* rb2  = (const float*)d_in[7];
  const float* lw   = (const float*)d_in[8];
  const float* lb   = (const float*)d_in[9];
  const float* bng  = (const float*)d_in[10];
  const float* bnb  = (const float*)d_in[11];
  float* out = (float*)d_out;

  const int n_img = in_sizes[0] / (3*34*34);   // B*32 = 16384
  const size_t faBytes = (size_t)n_img * 1024 * 2;   // 32 MB

  char* ws = (char*)d_ws;
  u16*  Fa = (u16*)ws;                    // [0, 32MB)
  u16*  F  = (u16*)(ws + faBytes);        // [32, 64MB) — dead after gather
  u16*  z  = (u16*)(ws + faBytes);        // [32, 64MB) — overwrites dead F
  char* sp = ws + 2*faBytes;              // smalls at 64MB
  float* e_buf   = (float*)sp;            // 640 B
  int*   idx_buf = (int*)(sp + 1024);     // 640 B
  float* stats   = (float*)(sp + 2048);   // 8 KB (sum | sumsq)
  u16*   Wb      = (u16*)(sp + 16384);    // 2 MB bf16 lin_w

  prep_convw_kernel<<<1025, 256, 0, stream>>>(vert, rw1, rb1, rw2, rb2, lw, Wb,
                                              e_buf, idx_buf, stats);
  conv_kernel<<<n_img, 256, 0, stream>>>(x, cw, cb, F);
  gather_kernel<<<n_img, 256, 0, stream>>>(F, e_buf, idx_buf, Fa);
  gemm_kernel<<<dim3(8, n_img/128), 256, 0, stream>>>(Fa, Wb, lb, z, stats);
  norm_kernel<<<n_img/2, 256, 0, stream>>>(z, stats, bng, bnb, 1.f/(float)n_img, out);
}